// Round 4
// baseline (218.246 us; speedup 1.0000x reference)
//
#include <hip/hip_runtime.h>
#include <stdint.h>

typedef float  float4v  __attribute__((ext_vector_type(4)));
typedef short  short8v  __attribute__((ext_vector_type(8)));
typedef unsigned short ushort4v __attribute__((ext_vector_type(4)));

// Problem constants (N=8192, n_in=256, m=256, k=8)
// GEMM: [8192 x 512] x [512 x 8192] with fused LSTM epilogue.

__device__ __forceinline__ unsigned short f2bf(float f) {
  union { float f; unsigned int u; } v; v.f = f;
  return (unsigned short)((v.u + 0x7FFFu + ((v.u >> 16) & 1u)) >> 16);
}

__device__ __forceinline__ float sigm(float x) {
  return __builtin_amdgcn_rcpf(1.0f + __expf(-x));
}
__device__ __forceinline__ float tanh_(float x) {
  return fmaf(2.0f, __builtin_amdgcn_rcpf(1.0f + __expf(-2.0f * x)), -1.0f);
}

__device__ __forceinline__ void gll16(const void* g, void* l) {
  __builtin_amdgcn_global_load_lds((const __attribute__((address_space(1))) void*)g,
                                   (__attribute__((address_space(3))) void*)l, 16, 0, 0);
}

#define BARRIER   asm volatile("s_barrier" ::: "memory")
#define WAITLGKM  asm volatile("s_waitcnt lgkmcnt(0)" ::: "memory")
#define WAITVM6   asm volatile("s_waitcnt vmcnt(6)" ::: "memory")
#define WAITVM0   asm volatile("s_waitcnt vmcnt(0)" ::: "memory")
#define PRIO1     __builtin_amdgcn_s_setprio(1)
#define PRIO0     __builtin_amdgcn_s_setprio(0)

// ------------- P1+L fused: A = [x|h] bf16 K-permuted + logits + softmaxes ---------
__global__ void prep_logits(const float* __restrict__ x, const float* __restrict__ h,
                            const float* __restrict__ u, const float* __restrict__ Wxz,
                            const float* __restrict__ Whz, const float* __restrict__ bxz,
                            const void* __restrict__ taup,
                            unsigned short* __restrict__ A,
                            float* __restrict__ z_out, float* __restrict__ qz_out) {
  int lane = threadIdx.x & 63;
  int n = blockIdx.x * 4 + (threadIdx.x >> 6);
  float4v xv = *(const float4v*)(x + (size_t)n * 256 + lane * 4);
  float4v hv = *(const float4v*)(h + (size_t)n * 256 + lane * 4);

  // ---- bf16 K-permuted A write: granule (w,si): lo4 = k{w*32+si*4..}, hi4 = +16
  {
    ushort4v xa, ha;
#pragma unroll
    for (int j = 0; j < 4; ++j) { xa[j] = f2bf(xv[j]); ha[j] = f2bf(hv[j]); }
    int w = lane >> 3, si = lane & 3, hi = (lane & 4) ? 4 : 0;
    unsigned short* dst = A + (size_t)n * 512 + w * 32 + si * 8 + hi;
    *(ushort4v*)dst = xa;
    *(ushort4v*)(dst + 256) = ha;
  }

  // ---- logits
  float p[8];
#pragma unroll
  for (int j = 0; j < 8; ++j) p[j] = 0.0f;
#pragma unroll
  for (int ii = 0; ii < 4; ++ii) {
    int i = lane * 4 + ii;
    float xs = xv[ii], hs = hv[ii];
#pragma unroll
    for (int j = 0; j < 8; ++j)
      p[j] += xs * Wxz[i * 8 + j] + hs * Whz[i * 8 + j];
  }
#pragma unroll
  for (int j = 0; j < 8; ++j)
    for (int off = 32; off > 0; off >>= 1) p[j] += __shfl_down(p[j], off, 64);

  if (lane == 0) {
    int   iv = ((const int*)taup)[0];
    float fv = ((const float*)taup)[0];
    float tau = (iv >= 1 && iv < 100000) ? (float)iv : fv;
    float tinv = 1.0f / tau;

    float logit[8], e[8];
    float mx = -1e30f;
#pragma unroll
    for (int j = 0; j < 8; ++j) { logit[j] = p[j] + bxz[j]; mx = fmaxf(mx, logit[j]); }
    float s = 0.0f;
#pragma unroll
    for (int j = 0; j < 8; ++j) { e[j] = __expf(logit[j] - mx); s += e[j]; }
    float inv = 1.0f / s;
#pragma unroll
    for (int j = 0; j < 8; ++j) qz_out[(size_t)n * 8 + j] = e[j] * inv;

    float t[8];
    float mt = -1e30f;
#pragma unroll
    for (int j = 0; j < 8; ++j) {
      float uu = u[(size_t)n * 8 + j];
      float g = -__logf(-__logf(uu + 1e-10f) + 1e-10f);
      t[j] = (logit[j] + g) * tinv;
      mt = fmaxf(mt, t[j]);
    }
    float s2 = 0.0f;
#pragma unroll
    for (int j = 0; j < 8; ++j) { e[j] = __expf(t[j] - mt); s2 += e[j]; }
    float inv2 = 1.0f / s2;
#pragma unroll
    for (int j = 0; j < 8; ++j) z_out[(size_t)n * 8 + j] = e[j] * inv2;
  }
}

// ---------------- P2: Bt[p][k'] bf16, col-permuted + K-permuted -------------------
// New gate-in-register mapping:
//   p(C) = (mm>>3)*256 + (g>>1)*128 + (g&1)*64 + (kk>>1)*16 + (kk&1)*8 + (mm&7)
// where C = g*2048 + kk*256 + mm.
__global__ void prep_Bt(const float* __restrict__ Wx, const float* __restrict__ Wh,
                        unsigned short* __restrict__ Bt) {
  __shared__ float tile[32][64];
  int tid = threadIdx.x;
  int wi = blockIdx.x & 15;           // k-window (32 k each)
  int C0 = (blockIdx.x >> 4) << 6;    // 64-col group
#pragma unroll
  for (int q = 0; q < 8; ++q) {
    int flat = q * 256 + tid;
    int i = flat >> 6, c = flat & 63;
    int ig = wi * 32 + i;
    float v = (ig < 256) ? Wx[(size_t)ig * 8192 + C0 + c]
                         : Wh[(size_t)(ig - 256) * 8192 + C0 + c];
    tile[i][c] = v;
  }
  __syncthreads();
  int cc = tid & 63, part = tid >> 6;
  int C = C0 + cc;
  int g = C >> 11, kk = (C >> 8) & 7, mm = C & 255;
  int p = ((mm >> 3) << 8) + ((g >> 1) << 7) + ((g & 1) << 6)
        + ((kk >> 1) << 4) + ((kk & 1) << 3) + (mm & 7);
  ushort4v oa, ob;
#pragma unroll
  for (int e = 0; e < 8; ++e) {
    int il = ((e >> 2) << 4) + (part << 2) + (e & 3);  // orig i within window
    unsigned short bv = f2bf(tile[il][cc]);
    if (e < 4) oa[e] = bv; else ob[e - 4] = bv;
  }
  unsigned short* dst = Bt + (size_t)p * 512 + wi * 32 + part * 8;
  *(ushort4v*)dst = oa;
  *(ushort4v*)(dst + 4) = ob;
}

// ---------------- G: persistent 256x256-tile 8-phase GEMM + fused epilogue --------
// Grid 256; block walks 4 cb-tiles (fixed rb). 8 waves = 2M x 4N.
// Wave rows: ha*128 + j*32 + wm*16 + gl*4 + r ; cols: hb*128 + n2*64 + wn*16 + ml
// col decode: gate g = hb*2+n2 ; kk = wn*2+(ml>>3) ; mml = ml&7
__global__ __launch_bounds__(512, 2) void gates_kernel(
    const unsigned short* __restrict__ A,   // [8192][512] bf16 K-permuted
    const unsigned short* __restrict__ Bt,  // [8192][512] bf16 col+K-permuted
    const float* __restrict__ c0g,          // [8192][256]
    const float* __restrict__ bias,         // [8192]
    const float* __restrict__ zg,           // [8192][8]
    float* __restrict__ h_out, float* __restrict__ c_out) {
  __shared__ char smem[131072];  // A: 4 slots x 16KB @0 ; B: 4 slots x 16KB @65536

  const int tid = threadIdx.x;
  const int lane = tid & 63, ml = lane & 15, gl = lane >> 4;
  const int wid = tid >> 6, wm = wid >> 2, wn = wid & 3;

  // persistent XCD-stripe mapping: xcd owns rb {4x..4x+3}; cb = (s>>2) + 8t
  const int xcd = blockIdx.x & 7;
  const int s_  = blockIdx.x >> 3;
  const int rb  = (xcd << 2) | (s_ & 3);
  int cb        = s_ >> 2;
  const int row0 = rb << 8;

  const char* Abp = (const char*)A + (size_t)rb * 262144;
  const char* Bb  = (const char*)Bt + (size_t)cb * 262144;

  // staging source offsets (16B-granule swizzle q' = q ^ (row&7))
  const int srow = tid >> 3, sg = tid & 7;
  const int soff = srow * 1024 + (((sg ^ (srow & 7))) << 4);

  // per-lane LDS fragment base pointers (imm offsets stay < 64KB)
  const char* pa0 = smem + ((wm << 4) + ml) * 128 + ((gl ^ (ml & 7)) << 4);
  const char* pa1 = smem + ((wm << 4) + ml) * 128 + (((4 | gl) ^ (ml & 7)) << 4);
  const char* pb0 = smem + 65536 + ((wn << 4) + ml) * 128 + ((gl ^ (ml & 7)) << 4);
  const char* pb1 = smem + 65536 + ((wn << 4) + ml) * 128 + (((4 | gl) ^ (ml & 7)) << 4);

#define STG(KTS, POS, BB) do { \
    const int isA_ = ((POS) == 0) || ((POS) == 3); \
    const int half_ = (POS) >= 2; \
    const int slot_ = (2 * (KTS) + half_) & 3; \
    const char* s__ = (isA_ ? Abp : (BB)) + half_ * 131072 + ((KTS) & 7) * 128 + soff; \
    char* d__ = smem + (isA_ ? 0 : 65536) + slot_ * 16384 + (tid << 4); \
    gll16(s__, d__); gll16(s__ + 65536, d__ + 8192); \
  } while (0)

#define RDA(KB, HF) { _Pragma("unroll") for (int j = 0; j < 4; ++j) { \
    afr[j][0] = *(const short8v*)(pa0 + (KB) * 32768 + (HF) * 16384 + j * 4096); \
    afr[j][1] = *(const short8v*)(pa1 + (KB) * 32768 + (HF) * 16384 + j * 4096); } }
#define RDB(KB, HF, BF) { _Pragma("unroll") for (int n2 = 0; n2 < 2; ++n2) { \
    BF[n2][0] = *(const short8v*)(pb0 + (KB) * 32768 + (HF) * 16384 + n2 * 8192); \
    BF[n2][1] = *(const short8v*)(pb1 + (KB) * 32768 + (HF) * 16384 + n2 * 8192); } }
#define MM16(AH, BH, BF) { _Pragma("unroll") for (int j = 0; j < 4; ++j) \
    _Pragma("unroll") for (int n2 = 0; n2 < 2; ++n2) { \
      acc[AH][BH][j][n2] = __builtin_amdgcn_mfma_f32_16x16x32_bf16(afr[j][0], BF[n2][0], acc[AH][BH][j][n2], 0, 0, 0); \
      acc[AH][BH][j][n2] = __builtin_amdgcn_mfma_f32_16x16x32_bf16(afr[j][1], BF[n2][1], acc[AH][BH][j][n2], 0, 0, 0); } }

  float4v acc[2][2][4][2];   // [ha][hb][j][n2]
  short8v afr[4][2];
  short8v bf0[2][2], bf1[2][2];

  // epilogue lane constants
  const int kkl = (wn << 1) | (ml >> 3);
  const int mml = ml & 7;

  // one-time stage of tile-0 kt0 (q'0..3)
  STG(0, 0, Bb); STG(0, 1, Bb); STG(0, 2, Bb); STG(0, 3, Bb);

  for (int t = 0; t < 4; ++t) {
    const char* BbN = Bb + (1 << 21);
    const bool last = (t == 3);

#pragma unroll
    for (int a = 0; a < 2; ++a)
#pragma unroll
      for (int b = 0; b < 2; ++b)
#pragma unroll
        for (int j = 0; j < 4; ++j)
#pragma unroll
          for (int c = 0; c < 2; ++c)
#pragma unroll
            for (int r = 0; r < 4; ++r) acc[a][b][j][c][r] = 0.0f;

    // stage kt1 A0,B0,B1 (q'4..6): outstanding reaches 14 -> wait leaves 6
    STG(1, 0, Bb); STG(1, 1, Bb); STG(1, 2, Bb);
    WAITVM6;
    BARRIER;

#pragma unroll
    for (int kt = 0; kt < 8; ++kt) {
      const int kb = kt & 1;

      // P0: A(half0), B(half0)
      RDA(kb, 0); RDB(kb, 0, bf0);
      if (kt <= 5) { STG(kt + 1, 3, Bb); }
      else if (kt == 6) { STG(7, 3, Bb); }
      else { if (!last) STG(8, 3, BbN); }
      BARRIER; WAITLGKM;
      PRIO1; MM16(0, 0, bf0); PRIO0;
      BARRIER;

      // P1: B(half1)
      RDB(kb, 1, bf1);
      if (kt <= 5) { STG(kt + 2, 0, Bb); }
      else if (kt == 6) { if (!last) STG(8, 0, BbN); }
      BARRIER; WAITLGKM;
      PRIO1; MM16(0, 1, bf1); PRIO0;
      BARRIER;

      // P2: A(half1)
      RDA(kb, 1);
      if (kt <= 5) { STG(kt + 2, 1, Bb); }
      else if (kt == 6) { if (!last) STG(8, 1, BbN); }
      BARRIER; WAITLGKM;
      PRIO1; MM16(1, 1, bf1); PRIO0;
      BARRIER;

      // P3: no reads (bf0 still live)
      if (kt <= 5) { STG(kt + 2, 2, Bb); WAITVM6; }
      else if (kt == 6) { if (!last) { STG(8, 2, BbN); WAITVM6; } else { WAITVM0; } }
      BARRIER;
      PRIO1; MM16(1, 0, bf0); PRIO0;
      BARRIER;
    }

    // ---------------- fused LSTM epilogue (slots A2/A3 are free => pbuf) ----------
    {
      const int mmg = (cb << 3) + mml;
      const float bI = bias[0 * 2048 + kkl * 256 + mmg];
      const float bG = bias[1 * 2048 + kkl * 256 + mmg];
      const float bF = bias[2 * 2048 + kkl * 256 + mmg];
      const float bO = bias[3 * 2048 + kkl * 256 + mmg];

      float hpart[2][4][4], cpart[2][4][4];
#pragma unroll
      for (int ha = 0; ha < 2; ++ha) {
#pragma unroll
        for (int j = 0; j < 4; ++j) {
          const int nb = row0 + ha * 128 + j * 32 + wm * 16 + gl * 4;
          // gates vertically in-register: I=acc[ha][0][j][0], G=[0][1], F=[1][0], O=[1][1]
#pragma unroll
          for (int r = 0; r < 4; ++r) {
            const int nrow = nb + r;
            float I = acc[ha][0][j][0][r] + bI;
            float G = acc[ha][0][j][1][r] + bG;
            float F = acc[ha][1][j][0][r] + bF;
            float O = acc[ha][1][j][1][r] + bO;
            float c0v = c0g[(size_t)nrow * 256 + mmg];
            float ct = fmaf(sigm(F), c0v, sigm(I) * tanh_(G));
            float ht = sigm(O) * tanh_(ct);
            float zv = zg[(size_t)nrow * 8 + kkl];
            float h1 = zv * ht, c1 = zv * ct;
            h1 += __shfl_xor(h1, 8, 64);    // combine the 2 kk owned by this wave
            c1 += __shfl_xor(c1, 8, 64);
            hpart[ha][j][r] = h1;
            cpart[ha][j][r] = c1;
          }
        }
      }

      float* pbuf = (float*)(smem + 32768);   // 32KB: [wn][256][8]
      const bool wr = ((ml & 8) == 0);
      // ---- pass 1: h
      if (wr) {
#pragma unroll
        for (int ha = 0; ha < 2; ++ha)
#pragma unroll
          for (int j = 0; j < 4; ++j)
#pragma unroll
            for (int r = 0; r < 4; ++r) {
              int rloc = ha * 128 + j * 32 + wm * 16 + gl * 4 + r;
              pbuf[wn * 2048 + rloc * 8 + mml] = hpart[ha][j][r];
            }
      }
      WAITLGKM; BARRIER;
#pragma unroll
      for (int i = 0; i < 4; ++i) {
        int idx = (i << 9) + tid;
        int rloc = idx >> 3, mm2 = idx & 7;
        float v = pbuf[rloc * 8 + mm2] + pbuf[2048 + rloc * 8 + mm2]
                + pbuf[4096 + rloc * 8 + mm2] + pbuf[6144 + rloc * 8 + mm2];
        h_out[(size_t)(row0 + rloc) * 256 + (cb << 3) + mm2] = v;
      }
      WAITLGKM; BARRIER;
      // ---- pass 2: c
      if (wr) {
#pragma unroll
        for (int ha = 0; ha < 2; ++ha)
#pragma unroll
          for (int j = 0; j < 4; ++j)
#pragma unroll
            for (int r = 0; r < 4; ++r) {
              int rloc = ha * 128 + j * 32 + wm * 16 + gl * 4 + r;
              pbuf[wn * 2048 + rloc * 8 + mml] = cpart[ha][j][r];
            }
      }
      WAITLGKM; BARRIER;
#pragma unroll
      for (int i = 0; i < 4; ++i) {
        int idx = (i << 9) + tid;
        int rloc = idx >> 3, mm2 = idx & 7;
        float v = pbuf[rloc * 8 + mm2] + pbuf[2048 + rloc * 8 + mm2]
                + pbuf[4096 + rloc * 8 + mm2] + pbuf[6144 + rloc * 8 + mm2];
        c_out[(size_t)(row0 + rloc) * 256 + (cb << 3) + mm2] = v;
      }
      WAITLGKM; BARRIER;   // pbuf region may be re-staged next tile
    }

    Bb += (1 << 21);
    cb += 8;
  }
#undef STG
#undef RDA
#undef RDB
#undef MM16
}

extern "C" void kernel_launch(void* const* d_in, const int* in_sizes, int n_in,
                              void* d_out, int out_size, void* d_ws, size_t ws_size,
                              hipStream_t stream) {
  const float* x   = (const float*)d_in[0];
  const float* h0  = (const float*)d_in[1];
  const float* c0  = (const float*)d_in[2];
  const float* u   = (const float*)d_in[3];
  const float* Wxz = (const float*)d_in[4];
  const float* Whz = (const float*)d_in[5];
  const float* Wx4 = (const float*)d_in[6];
  const float* Wh4 = (const float*)d_in[7];
  const float* bxz = (const float*)d_in[8];
  const float* b4  = (const float*)d_in[9];
  const void*  tau = d_in[10];

  float* out    = (float*)d_out;
  float* z_out  = out;                       // [8192][8]
  float* qz_out = out + 65536;               // [8192][8]
  float* h_out  = out + 131072;              // [8192][256]
  float* c_out  = out + 131072 + 2097152;    // [8192][256]

  unsigned short* A  = (unsigned short*)d_ws;       // 8.4MB
  unsigned short* Bt = A + 4194304;                 // 8.4MB

  prep_logits<<<2048, 256, 0, stream>>>(x, h0, u, Wxz, Whz, bxz, tau, A, z_out, qz_out);
  prep_Bt<<<2048, 256, 0, stream>>>(Wx4, Wh4, Bt);
  gates_kernel<<<256, 512, 0, stream>>>(A, Bt, c0, b4, z_out, h_out, c_out);
}

// Round 5
// 109.468 us; speedup vs baseline: 1.9937x; 1.9937x over previous
//
#include <hip/hip_runtime.h>
#include <stdint.h>

typedef float  float4v  __attribute__((ext_vector_type(4)));
typedef long long llong2v __attribute__((ext_vector_type(2)));
typedef unsigned int uint4v __attribute__((ext_vector_type(4)));

// Problem constants (N=8192, n_in=256, m=256, k=8)
// GEMM: [8192 x 512] x [512 x 8192] in fp8 e4m3 with fused LSTM epilogue.
// W is pre-scaled by 16 (e4m3 normal range); acc scaled by 1/16 in epilogue.
// K-granule layout within each 64-k window: byte = gl*16 + ks*8 + j
// (orig k = ks*32 + gl*8 + j). Same permutation on A and B => correct for
// any HW fragment k-mapping (symmetric contraction).

__device__ __forceinline__ unsigned int pk4fp8(float a, float b, float c, float d) {
  unsigned int p = (unsigned int)__builtin_amdgcn_cvt_pk_fp8_f32(a, b, 0, false);
  p = (unsigned int)__builtin_amdgcn_cvt_pk_fp8_f32(c, d, (int)p, true);
  return p;
}

__device__ __forceinline__ float sigm(float x) {
  return __builtin_amdgcn_rcpf(1.0f + __expf(-x));
}
__device__ __forceinline__ float tanh_(float x) {
  return fmaf(2.0f, __builtin_amdgcn_rcpf(1.0f + __expf(-2.0f * x)), -1.0f);
}

__device__ __forceinline__ void gll16(const void* g, void* l) {
  __builtin_amdgcn_global_load_lds((const __attribute__((address_space(1))) void*)g,
                                   (__attribute__((address_space(3))) void*)l, 16, 0, 0);
}

#define BARRIER   asm volatile("s_barrier" ::: "memory")
#define WAITLGKM  asm volatile("s_waitcnt lgkmcnt(0)" ::: "memory")
#define WAITVM3   asm volatile("s_waitcnt vmcnt(3)" ::: "memory")
#define WAITVM0   asm volatile("s_waitcnt vmcnt(0)" ::: "memory")
#define PRIO1     __builtin_amdgcn_s_setprio(1)
#define PRIO0     __builtin_amdgcn_s_setprio(0)

// ------------- P1+L fused: A = [x|h] fp8 K-granule-permuted + logits --------------
__global__ void prep_logits(const float* __restrict__ x, const float* __restrict__ h,
                            const float* __restrict__ u, const float* __restrict__ Wxz,
                            const float* __restrict__ Whz, const float* __restrict__ bxz,
                            const void* __restrict__ taup,
                            uint8_t* __restrict__ A,
                            float* __restrict__ z_out, float* __restrict__ qz_out) {
  int lane = threadIdx.x & 63;
  int n = blockIdx.x * 4 + (threadIdx.x >> 6);
  float4v xv = *(const float4v*)(x + (size_t)n * 256 + lane * 4);
  float4v hv = *(const float4v*)(h + (size_t)n * 256 + lane * 4);

  // fp8 A write: lane i covers orig k = 4i..4i+3 (x) and 256+4i.. (h)
  {
    unsigned int px = pk4fp8(xv[0], xv[1], xv[2], xv[3]);
    unsigned int ph = pk4fp8(hv[0], hv[1], hv[2], hv[3]);
    int koff = ((lane >> 4) << 6) + (((lane >> 1) & 3) << 4)
             + (((lane >> 3) & 1) << 3) + ((lane & 1) << 2);
    uint8_t* dst = A + (size_t)n * 512 + koff;
    *(unsigned int*)dst = px;
    *(unsigned int*)(dst + 256) = ph;
  }

  // ---- logits
  float p[8];
#pragma unroll
  for (int j = 0; j < 8; ++j) p[j] = 0.0f;
#pragma unroll
  for (int ii = 0; ii < 4; ++ii) {
    int i = lane * 4 + ii;
    float xs = xv[ii], hs = hv[ii];
#pragma unroll
    for (int j = 0; j < 8; ++j)
      p[j] += xs * Wxz[i * 8 + j] + hs * Whz[i * 8 + j];
  }
#pragma unroll
  for (int j = 0; j < 8; ++j)
    for (int off = 32; off > 0; off >>= 1) p[j] += __shfl_down(p[j], off, 64);

  if (lane == 0) {
    int   iv = ((const int*)taup)[0];
    float fv = ((const float*)taup)[0];
    float tau = (iv >= 1 && iv < 100000) ? (float)iv : fv;
    float tinv = 1.0f / tau;

    float logit[8], e[8];
    float mx = -1e30f;
#pragma unroll
    for (int j = 0; j < 8; ++j) { logit[j] = p[j] + bxz[j]; mx = fmaxf(mx, logit[j]); }
    float s = 0.0f;
#pragma unroll
    for (int j = 0; j < 8; ++j) { e[j] = __expf(logit[j] - mx); s += e[j]; }
    float inv = 1.0f / s;
#pragma unroll
    for (int j = 0; j < 8; ++j) qz_out[(size_t)n * 8 + j] = e[j] * inv;

    float t[8];
    float mt = -1e30f;
#pragma unroll
    for (int j = 0; j < 8; ++j) {
      float uu = u[(size_t)n * 8 + j];
      float g = -__logf(-__logf(uu + 1e-10f) + 1e-10f);
      t[j] = (logit[j] + g) * tinv;
      mt = fmaxf(mt, t[j]);
    }
    float s2 = 0.0f;
#pragma unroll
    for (int j = 0; j < 8; ++j) { e[j] = __expf(t[j] - mt); s2 += e[j]; }
    float inv2 = 1.0f / s2;
#pragma unroll
    for (int j = 0; j < 8; ++j) z_out[(size_t)n * 8 + j] = e[j] * inv2;
  }
}

// ---------------- P2: Bt[p][512B] fp8, col-permuted + K-granule-permuted ----------
// p(C) = (mm>>3)*256 + (g>>1)*128 + (g&1)*64 + (kk>>1)*16 + (kk&1)*8 + (mm&7)
// W scaled by 16 before fp8 conversion.
__global__ void prep_Bt(const float* __restrict__ Wx, const float* __restrict__ Wh,
                        uint8_t* __restrict__ Bt) {
  __shared__ float tile[64][64];
  int tid = threadIdx.x;
  int wi = blockIdx.x & 7;            // 64-k window
  int C0 = (blockIdx.x >> 3) << 6;    // 64-col group
#pragma unroll
  for (int qq = 0; qq < 16; ++qq) {
    int flat = qq * 256 + tid;
    int r = flat >> 6, c = flat & 63;
    int ig = wi * 64 + r;
    float v = (ig < 256) ? Wx[(size_t)ig * 8192 + C0 + c]
                         : Wh[(size_t)(ig - 256) * 8192 + C0 + c];
    tile[r][c] = v * 16.0f;
  }
  __syncthreads();
  int c = tid & 63, q = tid >> 6;
  int C = C0 + c;
  int g = C >> 11, kk = (C >> 8) & 7, mm = C & 255;
  int p = ((mm >> 3) << 8) | ((g >> 1) << 7) | ((g & 1) << 6)
        | ((kk >> 1) << 4) | ((kk & 1) << 3) | (mm & 7);
  uint4v o;
  o[0] = pk4fp8(tile[q * 8 + 0][c], tile[q * 8 + 1][c], tile[q * 8 + 2][c], tile[q * 8 + 3][c]);
  o[1] = pk4fp8(tile[q * 8 + 4][c], tile[q * 8 + 5][c], tile[q * 8 + 6][c], tile[q * 8 + 7][c]);
  o[2] = pk4fp8(tile[32 + q * 8 + 0][c], tile[32 + q * 8 + 1][c], tile[32 + q * 8 + 2][c], tile[32 + q * 8 + 3][c]);
  o[3] = pk4fp8(tile[32 + q * 8 + 4][c], tile[32 + q * 8 + 5][c], tile[32 + q * 8 + 6][c], tile[32 + q * 8 + 7][c]);
  *(uint4v*)(Bt + (size_t)p * 512 + wi * 64 + q * 16) = o;
}

// ---------------- G: fp8 256x256-tile 8-phase GEMM + fused LSTM epilogue ----------
// 8 waves = 2M x 4N. Rows: ha*128 + j*32 + wm*16 + gl*4 + r ; cols: hb*128 + n2*64 + wn*16 + ml
// gate g = hb*2+n2 ; kk = wn*2+(ml>>3) ; mml = ml&7
__global__ __launch_bounds__(512, 2) void gates_kernel(
    const uint8_t* __restrict__ A,    // [8192][512B] fp8, K-granule layout
    const uint8_t* __restrict__ Bt,   // [8192][512B] fp8, col+K-granule layout
    const float* __restrict__ c0g,    // [8192][256]
    const float* __restrict__ bias,   // [8192]
    const float* __restrict__ zg,     // [8192][8]
    float* __restrict__ h_out, float* __restrict__ c_out) {
  __shared__ char smem[65536];  // A: 4 slots x 8KB @0 ; B: 4 slots x 8KB @32768

  const int tid = threadIdx.x;
  const int lane = tid & 63, ml = lane & 15, gl = lane >> 4;
  const int wid = tid >> 6, wm = wid >> 2, wn = wid & 3;

  // XCD-stripe grid mapping (verified in R3): xcd owns rb {4x..4x+3}, cb outer
  const int xcd = blockIdx.x & 7;
  const int j_  = blockIdx.x >> 3;
  const int cb  = j_ >> 2;
  const int rb  = (xcd << 2) | (j_ & 3);
  const int row0 = rb << 8;

  const uint8_t* Abp = A + (size_t)rb * 131072;   // 256 rows x 512B
  const uint8_t* Bbp = Bt + (size_t)cb * 131072;

  // staging: half-tile = 128 rows x 64B = 8KB = 512 granules; 1 gll16/thread
  const int ssrc = (tid >> 2) * 512 + (tid & 3) * 16;

  // fragment LDS bases (dense 1KB-per-16-row-block reads; conflict-free)
  const char* pa = smem + ((wm << 4) + ml) * 64 + (gl << 4);
  const char* pb = smem + 32768 + ((wn << 4) + ml) * 64 + (gl << 4);

#define STG(KTS, POS) do { \
    const int isA_ = ((POS) == 0) || ((POS) == 3); \
    const int half_ = (POS) >= 2; \
    const int slot_ = (2 * (KTS) + half_) & 3; \
    const uint8_t* s__ = (isA_ ? Abp : Bbp) + half_ * 65536 + ((KTS) & 7) * 64 + ssrc; \
    char* d__ = smem + (isA_ ? 0 : 32768) + slot_ * 8192 + (tid << 4); \
    gll16(s__, d__); \
  } while (0)

#define RDA(KB, HF) { _Pragma("unroll") for (int j = 0; j < 4; ++j) \
    af[j] = *(const llong2v*)(pa + (KB) * 16384 + (HF) * 8192 + j * 2048); }
#define RDB(KB, HF, BF) { _Pragma("unroll") for (int n2 = 0; n2 < 2; ++n2) \
    BF[n2] = *(const llong2v*)(pb + (KB) * 16384 + (HF) * 8192 + n2 * 4096); }
#define MM16(AH, BH, BF) { _Pragma("unroll") for (int j = 0; j < 4; ++j) \
    _Pragma("unroll") for (int n2 = 0; n2 < 2; ++n2) { \
      acc[AH][BH][j][n2] = __builtin_amdgcn_mfma_f32_16x16x32_fp8_fp8(af[j][0], BF[n2][0], acc[AH][BH][j][n2], 0, 0, 0); \
      acc[AH][BH][j][n2] = __builtin_amdgcn_mfma_f32_16x16x32_fp8_fp8(af[j][1], BF[n2][1], acc[AH][BH][j][n2], 0, 0, 0); } }

  float4v acc[2][2][4][2];   // [ha][hb][j][n2]
#pragma unroll
  for (int a = 0; a < 2; ++a)
#pragma unroll
    for (int b = 0; b < 2; ++b)
#pragma unroll
      for (int j = 0; j < 4; ++j)
#pragma unroll
        for (int c = 0; c < 2; ++c)
#pragma unroll
          for (int r = 0; r < 4; ++r) acc[a][b][j][c][r] = 0.0f;

  llong2v af[4];
  llong2v bf0[2], bf1[2];

  // prologue: kt0 complete (4) + kt1 A0,B0,B1 (3) -> 7 outstanding, wait to 3
  STG(0, 0); STG(0, 1); STG(0, 2); STG(0, 3);
  STG(1, 0); STG(1, 1); STG(1, 2);
  WAITVM3;
  BARRIER;

#pragma unroll
  for (int kt = 0; kt < 8; ++kt) {
    const int kb = kt & 1;

    // P0: A(half0), B(half0)
    RDA(kb, 0); RDB(kb, 0, bf0);
    if (kt <= 6) STG(kt + 1, 3);
    BARRIER; WAITLGKM;
    PRIO1; MM16(0, 0, bf0); PRIO0;
    BARRIER;

    // P1: B(half1)
    RDB(kb, 1, bf1);
    if (kt <= 5) STG(kt + 2, 0);
    BARRIER; WAITLGKM;
    PRIO1; MM16(0, 1, bf1); PRIO0;
    BARRIER;

    // P2: A(half1)
    RDA(kb, 1);
    if (kt <= 5) STG(kt + 2, 1);
    BARRIER; WAITLGKM;
    PRIO1; MM16(1, 1, bf1); PRIO0;
    BARRIER;

    // P3: no reads (bf0 still live)
    if (kt <= 5) { STG(kt + 2, 2); WAITVM3; }
    else if (kt == 6) { WAITVM0; }
    BARRIER;
    PRIO1; MM16(1, 0, bf0); PRIO0;
    BARRIER;
  }
#undef STG
#undef RDA
#undef RDB
#undef MM16

  // ---------------- fused LSTM epilogue (all LDS reads done; reuse smem) ----------
  const int kkl = (wn << 1) | (ml >> 3);
  const int mml = ml & 7;
  {
    const int mmg = (cb << 3) + mml;
    const float bI = bias[0 * 2048 + kkl * 256 + mmg];
    const float bG = bias[1 * 2048 + kkl * 256 + mmg];
    const float bF = bias[2 * 2048 + kkl * 256 + mmg];
    const float bO = bias[3 * 2048 + kkl * 256 + mmg];
    const float s16 = 0.0625f;   // undo W*16 pre-scale

    float hpart[2][4][4], cpart[2][4][4];
#pragma unroll
    for (int ha = 0; ha < 2; ++ha) {
#pragma unroll
      for (int j = 0; j < 4; ++j) {
        const int nb = row0 + ha * 128 + j * 32 + wm * 16 + gl * 4;
        // gates in-register: I=acc[ha][0][j][0], G=[0][1], F=[1][0], O=[1][1]
#pragma unroll
        for (int r = 0; r < 4; ++r) {
          const int nrow = nb + r;
          float I = fmaf(acc[ha][0][j][0][r], s16, bI);
          float G = fmaf(acc[ha][0][j][1][r], s16, bG);
          float F = fmaf(acc[ha][1][j][0][r], s16, bF);
          float O = fmaf(acc[ha][1][j][1][r], s16, bO);
          float c0v = c0g[(size_t)nrow * 256 + mmg];
          float ct = fmaf(sigm(F), c0v, sigm(I) * tanh_(G));
          float ht = sigm(O) * tanh_(ct);
          float zv = zg[(size_t)nrow * 8 + kkl];
          float h1 = zv * ht, c1 = zv * ct;
          h1 += __shfl_xor(h1, 8, 64);    // combine the wave's 2 kk
          c1 += __shfl_xor(c1, 8, 64);
          hpart[ha][j][r] = h1;
          cpart[ha][j][r] = c1;
        }
      }
    }

    float* pbuf = (float*)smem;   // 32KB: [wn][256][8]
    const bool wr = ((ml & 8) == 0);
    // ---- pass 1: h
    if (wr) {
#pragma unroll
      for (int ha = 0; ha < 2; ++ha)
#pragma unroll
        for (int j = 0; j < 4; ++j)
#pragma unroll
          for (int r = 0; r < 4; ++r) {
            int rloc = ha * 128 + j * 32 + wm * 16 + gl * 4 + r;
            pbuf[wn * 2048 + rloc * 8 + mml] = hpart[ha][j][r];
          }
    }
    WAITLGKM; BARRIER;
#pragma unroll
    for (int i = 0; i < 4; ++i) {
      int idx = (i << 9) + tid;
      int rloc = idx >> 3, mm2 = idx & 7;
      float v = pbuf[rloc * 8 + mm2] + pbuf[2048 + rloc * 8 + mm2]
              + pbuf[4096 + rloc * 8 + mm2] + pbuf[6144 + rloc * 8 + mm2];
      h_out[(size_t)(row0 + rloc) * 256 + (cb << 3) + mm2] = v;
    }
    WAITLGKM; BARRIER;
    // ---- pass 2: c
    if (wr) {
#pragma unroll
      for (int ha = 0; ha < 2; ++ha)
#pragma unroll
        for (int j = 0; j < 4; ++j)
#pragma unroll
          for (int r = 0; r < 4; ++r) {
            int rloc = ha * 128 + j * 32 + wm * 16 + gl * 4 + r;
            pbuf[wn * 2048 + rloc * 8 + mml] = cpart[ha][j][r];
          }
    }
    WAITLGKM; BARRIER;
#pragma unroll
    for (int i = 0; i < 4; ++i) {
      int idx = (i << 9) + tid;
      int rloc = idx >> 3, mm2 = idx & 7;
      float v = pbuf[rloc * 8 + mm2] + pbuf[2048 + rloc * 8 + mm2]
              + pbuf[4096 + rloc * 8 + mm2] + pbuf[6144 + rloc * 8 + mm2];
      c_out[(size_t)(row0 + rloc) * 256 + (cb << 3) + mm2] = v;
    }
  }
}

extern "C" void kernel_launch(void* const* d_in, const int* in_sizes, int n_in,
                              void* d_out, int out_size, void* d_ws, size_t ws_size,
                              hipStream_t stream) {
  const float* x   = (const float*)d_in[0];
  const float* h0  = (const float*)d_in[1];
  const float* c0  = (const float*)d_in[2];
  const float* u   = (const float*)d_in[3];
  const float* Wxz = (const float*)d_in[4];
  const float* Whz = (const float*)d_in[5];
  const float* Wx4 = (const float*)d_in[6];
  const float* Wh4 = (const float*)d_in[7];
  const float* bxz = (const float*)d_in[8];
  const float* b4  = (const float*)d_in[9];
  const void*  tau = d_in[10];

  float* out    = (float*)d_out;
  float* z_out  = out;                       // [8192][8]
  float* qz_out = out + 65536;               // [8192][8]
  float* h_out  = out + 131072;              // [8192][256]
  float* c_out  = out + 131072 + 2097152;    // [8192][256]

  uint8_t* A  = (uint8_t*)d_ws;              // 4MB fp8
  uint8_t* Bt = A + 4194304;                 // 4MB fp8

  prep_logits<<<2048, 256, 0, stream>>>(x, h0, u, Wxz, Whz, bxz, tau, A, z_out, qz_out);
  prep_Bt<<<1024, 256, 0, stream>>>(Wx4, Wh4, Bt);
  gates_kernel<<<1024, 512, 0, stream>>>(A, Bt, c0, b4, z_out, h_out, c_out);
}